// Round 7
// baseline (118.894 us; speedup 1.0000x reference)
//
#include <hip/hip_runtime.h>

#define DD 512
#define MROWS 384            // 4 batches * 96 nodes
#define EPSF 1e-5f
#define INVN (1.0f / 96.0f)

typedef short short8v __attribute__((ext_vector_type(8)));
typedef float f32x4   __attribute__((ext_vector_type(4)));

// round-to-nearest-even f32 -> bf16 (raw ushort)
static __device__ __forceinline__ unsigned short f2bf(float x) {
    union { float f; unsigned int u; } v; v.f = x;
    unsigned int r = v.u + 0x7fffu + ((v.u >> 16) & 1u);
    return (unsigned short)(r >> 16);
}

// ---------------------------------------------------------------------------
// K1: z=0..5 -> transpose+convert weight mat z (l=z/3, {W1a,W1b,W2}) into
//     WT[z] as bf16 [n][k]. z=6: y<12 -> h0 -> bf16; y==12 -> cnt[r]=sum_j adj.
// grid (16,16,7), block (32,8). 33-padded LDS transpose tile (R5-proven).
// ---------------------------------------------------------------------------
__global__ __launch_bounds__(256) void convert_all(
    const float* __restrict__ W1a, const float* __restrict__ W1b,
    const float* __restrict__ W2, const float* __restrict__ h0,
    const float* __restrict__ adj,
    unsigned short* __restrict__ WT, unsigned short* __restrict__ Hbf,
    float* __restrict__ CNT)
{
    const int tx = threadIdx.x, ty = threadIdx.y;
    const int z  = blockIdx.z;
    const int c0 = blockIdx.x * 32, r0 = blockIdx.y * 32;

    if (z == 6) {
        if (blockIdx.y < 12) {                    // h0 -> bf16 (384x512)
#pragma unroll
            for (int i = 0; i < 4; ++i) {
                const int r = r0 + ty + 8 * i;
                Hbf[(size_t)r * DD + c0 + tx] = f2bf(h0[(size_t)r * DD + c0 + tx]);
            }
        } else if (blockIdx.y == 12) {            // cnt: 16 blocks * 4 waves * 6 rows
            const int tid  = ty * 32 + tx;
            const int lane = tid & 63;
            const int wv   = tid >> 6;
            const int rb   = (blockIdx.x * 4 + wv) * 6;
#pragma unroll
            for (int q = 0; q < 6; ++q) {
                const float* mrow = adj + (size_t)(rb + q) * 96;
                float v = mrow[lane];
                if (lane < 32) v += mrow[64 + lane];
#pragma unroll
                for (int off = 32; off > 0; off >>= 1) v += __shfl_xor(v, off);
                if (lane == 0) CNT[rb + q] = v;
            }
        }
        return;
    }

    __shared__ float t[32][33];
    const int l = z / 3, w = z % 3;
    const float* __restrict__ src =
        (w == 0 ? W1a : (w == 1 ? W1b : W2)) + (size_t)l * DD * DD;
    unsigned short* __restrict__ dst = WT + (size_t)z * DD * DD;

#pragma unroll
    for (int i = 0; i < 4; ++i)
        t[ty + 8 * i][tx] = src[(size_t)(r0 + ty + 8 * i) * DD + c0 + tx];
    __syncthreads();
#pragma unroll
    for (int i = 0; i < 4; ++i)
        dst[(size_t)(c0 + ty + 8 * i) * DD + r0 + tx] = f2bf(t[tx][ty + 8 * i]);
}

// ---------------------------------------------------------------------------
// K2 (per layer): block = (batch b, 32-col d-slice). Computes
//   A  = Hbf@Wa + b1   (96 x 32, LDS)
//   Bb = Hbf@Wb        (96 x 32, LDS)
// then s[b,i,d] = sum_j adj[b,i,j]*relu(A[i,d]+Bb[j,d]) -> Sbf (bf16 global).
// grid (4,16), 512 threads (8 waves). Waves 0-3 -> 12 A-tiles, 4-7 -> 12 B-tiles.
// ---------------------------------------------------------------------------
__global__ __launch_bounds__(512) void layer_front(
    const unsigned short* __restrict__ Hbf,
    const unsigned short* __restrict__ WaT,
    const unsigned short* __restrict__ WbT,
    const float* __restrict__ b1l, const float* __restrict__ adj,
    unsigned short* __restrict__ Sbf)
{
    __shared__ float As[96][32];     // 12 KB
    __shared__ float Bs[96][32];     // 12 KB
    __shared__ float msh[96][96];    // 36 KB

    const int tid = threadIdx.x;
    const int b   = blockIdx.x;
    const int d0  = blockIdx.y * 32;

    // stage adj[b] (9216 floats, 18 per thread, coalesced)
    const float* __restrict__ ab = adj + (size_t)b * 96 * 96;
#pragma unroll
    for (int s = 0; s < 18; ++s) {
        const int t = tid + s * 512;
        msh[t / 96][t % 96] = ab[t];
    }

    // GEMM: 24 tiles of 16x16, K=512
    const int lane = tid & 63;
    const int wv   = tid >> 6;
    const int lo = lane & 15, hi = lane >> 4;
    const int isB  = wv >= 4;
    const unsigned short* __restrict__ Wt = isB ? WbT : WaT;
    float (* __restrict__ dst)[32] = isB ? Bs : As;

    for (int i = 0; i < 3; ++i) {
        const int tt = (wv & 3) * 3 + i;          // 0..11
        const int mt = tt % 6;                    // m-tile (6 x 16 = 96 rows)
        const int nt = tt / 6;                    // n-tile (2 x 16 = 32 cols)
        const unsigned short* ap = Hbf + (size_t)(b * 96 + mt * 16 + lo) * DD + 8 * hi;
        const unsigned short* bp = Wt  + (size_t)(d0 + nt * 16 + lo) * DD + 8 * hi;
        f32x4 acc = {0.f, 0.f, 0.f, 0.f};
#pragma unroll
        for (int k0 = 0; k0 < DD; k0 += 32)
            acc = __builtin_amdgcn_mfma_f32_16x16x32_bf16(
                *(const short8v*)(ap + k0), *(const short8v*)(bp + k0), acc, 0, 0, 0);
        const int cl = nt * 16 + lo;              // 0..31 local col
        const float bias = isB ? 0.f : b1l[d0 + cl];
        const int rb = mt * 16 + 4 * hi;
#pragma unroll
        for (int q = 0; q < 4; ++q)
            dst[rb + q][cl] = acc[q] + bias;
    }
    __syncthreads();

    // relusum: thread -> (6 rows, 1 col). dd = tid&31, ig = tid>>5 (16 groups)
    const int dd = tid & 31;
    const int i0 = (tid >> 5) * 6;
    float a6[6], s6[6];
#pragma unroll
    for (int q = 0; q < 6; ++q) { a6[q] = As[i0 + q][dd]; s6[q] = 0.f; }
#pragma unroll 4
    for (int j = 0; j < 96; ++j) {
        const float bv = Bs[j][dd];
#pragma unroll
        for (int q = 0; q < 6; ++q)
            s6[q] = fmaf(msh[i0 + q][j], fmaxf(a6[q] + bv, 0.f), s6[q]);
    }
#pragma unroll
    for (int q = 0; q < 6; ++q)
        Sbf[(size_t)(b * 96 + i0 + q) * DD + d0 + dd] = f2bf(s6[q]);
}

// ---------------------------------------------------------------------------
// K3 (per layer): block = 16 rows x all 512 cols.
//   U = hin + INVN*(Sbf@W2 + cnt*b2)  -> LDS, then per-row LayerNorm
//   (+ optional clip, + optional bf16 emit for next layer's A-operand).
// grid (24), 512 threads (8 waves). Wave w: 4 n-tiles n0=(w*4+i)*16; LN: 2 rows.
// ---------------------------------------------------------------------------
__global__ __launch_bounds__(512) void layer_back(
    const unsigned short* __restrict__ Sbf,
    const unsigned short* __restrict__ W2T,
    const float* __restrict__ b2l, const float* __restrict__ cnt,
    const float* __restrict__ hin, const float* __restrict__ gamma,
    const float* __restrict__ beta, float* __restrict__ hout,
    unsigned short* __restrict__ hbf_out, int doClip)
{
    __shared__ float Us[16][512];    // 32 KB

    const int tid  = threadIdx.x;
    const int m0   = blockIdx.x * 16;
    const int lane = tid & 63;
    const int wv   = tid >> 6;
    const int lo = lane & 15, hi = lane >> 4;

    for (int i = 0; i < 4; ++i) {
        const int n0 = (wv * 4 + i) * 16;
        const unsigned short* ap = Sbf + (size_t)(m0 + lo) * DD + 8 * hi;
        const unsigned short* bp = W2T + (size_t)(n0 + lo) * DD + 8 * hi;
        f32x4 acc = {0.f, 0.f, 0.f, 0.f};
#pragma unroll
        for (int k0 = 0; k0 < DD; k0 += 32)
            acc = __builtin_amdgcn_mfma_f32_16x16x32_bf16(
                *(const short8v*)(ap + k0), *(const short8v*)(bp + k0), acc, 0, 0, 0);
        const int col = n0 + lo;
        const float b2c = b2l[col];
#pragma unroll
        for (int q = 0; q < 4; ++q) {
            const int rr = 4 * hi + q;
            const int r  = m0 + rr;
            Us[rr][col] = hin[(size_t)r * DD + col] + INVN * acc[q]
                        + (cnt[r] * INVN) * b2c;
        }
    }
    __syncthreads();

    // LayerNorm: wave w handles rows wv*2, wv*2+1 (shfl-only, R5/R6-verified math)
#pragma unroll
    for (int rr = wv * 2; rr <= wv * 2 + 1; ++rr) {
        const int r = m0 + rr;
        const float4 x0 = *(const float4*)&Us[rr][lane * 8];
        const float4 x1 = *(const float4*)&Us[rr][lane * 8 + 4];
        float s = x0.x + x0.y + x0.z + x0.w + x1.x + x1.y + x1.z + x1.w;
#pragma unroll
        for (int off = 32; off > 0; off >>= 1) s += __shfl_xor(s, off);
        const float mu = s * (1.0f / 512.0f);
        const float d0 = x0.x - mu, d1 = x0.y - mu, d2 = x0.z - mu, d3 = x0.w - mu;
        const float d4 = x1.x - mu, d5 = x1.y - mu, d6 = x1.z - mu, d7 = x1.w - mu;
        float q = d0*d0 + d1*d1 + d2*d2 + d3*d3 + d4*d4 + d5*d5 + d6*d6 + d7*d7;
#pragma unroll
        for (int off = 32; off > 0; off >>= 1) q += __shfl_xor(q, off);
        const float rs = rsqrtf(q * (1.0f / 512.0f) + EPSF);

        const float4 g0 = *(const float4*)(gamma + lane * 8);
        const float4 g1 = *(const float4*)(gamma + lane * 8 + 4);
        const float4 t0 = *(const float4*)(beta + lane * 8);
        const float4 t1 = *(const float4*)(beta + lane * 8 + 4);
        float y0 = d0*rs*g0.x + t0.x, y1 = d1*rs*g0.y + t0.y;
        float y2 = d2*rs*g0.z + t0.z, y3 = d3*rs*g0.w + t0.w;
        float y4 = d4*rs*g1.x + t1.x, y5 = d5*rs*g1.y + t1.y;
        float y6 = d6*rs*g1.z + t1.z, y7 = d7*rs*g1.w + t1.w;
        if (doClip) {
            y0 = fminf(fmaxf(y0, -100.f), 100.f); y1 = fminf(fmaxf(y1, -100.f), 100.f);
            y2 = fminf(fmaxf(y2, -100.f), 100.f); y3 = fminf(fmaxf(y3, -100.f), 100.f);
            y4 = fminf(fmaxf(y4, -100.f), 100.f); y5 = fminf(fmaxf(y5, -100.f), 100.f);
            y6 = fminf(fmaxf(y6, -100.f), 100.f); y7 = fminf(fmaxf(y7, -100.f), 100.f);
        }
        float4 o0 = {y0, y1, y2, y3}, o1 = {y4, y5, y6, y7};
        *(float4*)(hout + (size_t)r * DD + lane * 8)     = o0;
        *(float4*)(hout + (size_t)r * DD + lane * 8 + 4) = o1;
        if (hbf_out) {
            uint4 u;
            u.x = (unsigned)f2bf(y0) | ((unsigned)f2bf(y1) << 16);
            u.y = (unsigned)f2bf(y2) | ((unsigned)f2bf(y3) << 16);
            u.z = (unsigned)f2bf(y4) | ((unsigned)f2bf(y5) << 16);
            u.w = (unsigned)f2bf(y6) | ((unsigned)f2bf(y7) << 16);
            *(uint4*)(hbf_out + (size_t)r * DD + lane * 8) = u;
        }
    }
}

// ---------------------------------------------------------------------------
extern "C" void kernel_launch(void* const* d_in, const int* in_sizes, int n_in,
                              void* d_out, int out_size, void* d_ws, size_t ws_size,
                              hipStream_t stream)
{
    const float* h0    = (const float*)d_in[0];  // (4,96,512)
    const float* adj   = (const float*)d_in[1];  // (4,96,96)
    const float* W1a   = (const float*)d_in[2];  // (2,512,512)
    const float* W1b   = (const float*)d_in[3];  // (2,512,512)
    const float* b1    = (const float*)d_in[4];  // (2,512)
    const float* W2    = (const float*)d_in[5];  // (2,512,512)
    const float* b2    = (const float*)d_in[6];  // (2,512)
    const float* gamma = (const float*)d_in[7];  // (512)
    const float* beta  = (const float*)d_in[8];  // (512)
    float* out = (float*)d_out;                  // (4,96,512)

    char* p = (char*)d_ws;
    unsigned short* WT  = (unsigned short*)p;  p += 6u * DD * DD * 2;   // 3.00 MB
    unsigned short* Hbf = (unsigned short*)p;  p += MROWS * DD * 2;     // 384 KB
    unsigned short* Sbf = (unsigned short*)p;  p += MROWS * DD * 2;     // 384 KB
    float* H1  = (float*)p;  p += MROWS * DD * 4;                       // 768 KB
    float* CNT = (float*)p;                                             // 1.5 KB

    convert_all<<<dim3(16, 16, 7), dim3(32, 8), 0, stream>>>(
        W1a, W1b, W2, h0, adj, WT, Hbf, CNT);

    for (int l = 0; l < 2; ++l) {
        const unsigned short* waT = WT + (size_t)(l * 3 + 0) * DD * DD;
        const unsigned short* wbT = WT + (size_t)(l * 3 + 1) * DD * DD;
        const unsigned short* w2T = WT + (size_t)(l * 3 + 2) * DD * DD;
        const float* hin = (l == 0) ? h0 : H1;
        float* hout = (l == 0) ? H1 : out;
        unsigned short* hbf_next = (l == 0) ? Hbf : nullptr;

        layer_front<<<dim3(4, 16), 512, 0, stream>>>(
            Hbf, waT, wbT, b1 + (size_t)l * DD, adj, Sbf);
        layer_back<<<dim3(24), 512, 0, stream>>>(
            Sbf, w2T, b2 + (size_t)l * DD, CNT, hin, gamma, beta, hout,
            hbf_next, l == 1);
    }
}